// Round 1
// baseline (237.735 us; speedup 1.0000x reference)
//
#include <hip/hip_runtime.h>
#include <math.h>

#define BB 128
#define NN 256
#define WW 64
#define DD 128
#define KK 20
#define LL (BB*WW)   // 8192
#define CT 16        // cov tile

// ---------------- Kernel A: per-node means of xr (row n = data[:,n,:] flattened) ----------------
__global__ void k_mean(const float* __restrict__ data, double* __restrict__ mean) {
    int n = blockIdx.x;
    int t = threadIdx.x;                  // 256 threads
    double s = 0.0;
    for (int c = 0; c < LL / 256; ++c) {
        int l = t + c * 256;
        int b = l >> 6, w = l & 63;
        s += (double)data[(b * NN + n) * WW + w];
    }
    for (int off = 32; off; off >>= 1) s += __shfl_down(s, off);
    __shared__ double red[4];
    int lane = t & 63, wid = t >> 6;
    if (lane == 0) red[wid] = s;
    __syncthreads();
    if (t == 0) mean[n] = (red[0] + red[1] + red[2] + red[3]) / (double)LL;
}

// ---------------- Kernel B: emb stats: e_em_i, e_em_j, ||emb||^2 ----------------
__global__ void k_embstats(const float* __restrict__ emb,
                           const float* __restrict__ att_em_i,
                           const float* __restrict__ att_em_j,
                           float* __restrict__ eemi, float* __restrict__ eemj,
                           double* __restrict__ nrm2) {
    int n = blockIdx.x;
    int t = threadIdx.x;                  // 128 threads
    float e = emb[n * DD + t];
    float pi = e * att_em_i[t];
    float pj = e * att_em_j[t];
    double pn = (double)e * (double)e;
    for (int off = 32; off; off >>= 1) {
        pi += __shfl_down(pi, off);
        pj += __shfl_down(pj, off);
        pn += __shfl_down(pn, off);
    }
    __shared__ float ri[2], rj[2];
    __shared__ double rn[2];
    int lane = t & 63, wid = t >> 6;
    if (lane == 0) { ri[wid] = pi; rj[wid] = pj; rn[wid] = pn; }
    __syncthreads();
    if (t == 0) { eemi[n] = ri[0] + ri[1]; eemj[n] = rj[0] + rj[1]; nrm2[n] = rn[0] + rn[1]; }
}

// ---------------- Kernel C: covariance (fp64, raw moments), 16x16 tiles, double-buffered LDS ----
__global__ __launch_bounds__(256) void k_cov(const float* __restrict__ data,
                                             const double* __restrict__ mean,
                                             double* __restrict__ cov) {
    int i0 = blockIdx.y * CT, j0 = blockIdx.x * CT;
    int t = threadIdx.x;                  // 256 threads
    int ti = t >> 4, tj = t & 15;
    __shared__ float A[2][CT][WW + 1], Bt[2][CT][WW + 1];

    // stage chunk 0 (chunk b = batch b: 64 contiguous floats per row)
    {
        #pragma unroll
        for (int e = 0; e < 4; ++e) {
            int idx = t + e * 256;
            int r = idx >> 6, w = idx & 63;
            A[0][r][w]  = data[(0 * NN + i0 + r) * WW + w];
            Bt[0][r][w] = data[(0 * NN + j0 + r) * WW + w];
        }
    }
    __syncthreads();

    double acc0 = 0, acc1 = 0, acc2 = 0, acc3 = 0;
    for (int b = 0; b < BB; ++b) {
        int p = b & 1;
        float ra[4], rb[4];
        if (b + 1 < BB) {
            #pragma unroll
            for (int e = 0; e < 4; ++e) {
                int idx = t + e * 256;
                int r = idx >> 6, w = idx & 63;
                ra[e] = data[((b + 1) * NN + i0 + r) * WW + w];
                rb[e] = data[((b + 1) * NN + j0 + r) * WW + w];
            }
        }
        #pragma unroll
        for (int w = 0; w < WW; w += 4) {
            acc0 += (double)A[p][ti][w + 0] * (double)Bt[p][tj][w + 0];
            acc1 += (double)A[p][ti][w + 1] * (double)Bt[p][tj][w + 1];
            acc2 += (double)A[p][ti][w + 2] * (double)Bt[p][tj][w + 2];
            acc3 += (double)A[p][ti][w + 3] * (double)Bt[p][tj][w + 3];
        }
        __syncthreads();
        if (b + 1 < BB) {
            #pragma unroll
            for (int e = 0; e < 4; ++e) {
                int idx = t + e * 256;
                int r = idx >> 6, w = idx & 63;
                A[p ^ 1][r][w]  = ra[e];
                Bt[p ^ 1][r][w] = rb[e];
            }
        }
        __syncthreads();
    }
    double s = (acc0 + acc1) + (acc2 + acc3);
    int i = i0 + ti, j = j0 + tj;
    s -= (double)LL * mean[i] * mean[j];
    cov[i * NN + j] = s;
}

// ---------------- Kernel D: sim = 0.7*cos + 0.3*corr (fp64) -> fp32, then top-20 per row --------
__global__ void k_sim_topk(const float* __restrict__ emb,
                           const double* __restrict__ nrm2,
                           const double* __restrict__ cov,
                           int* __restrict__ topk) {
    int i = blockIdx.x;
    int t = threadIdx.x;                  // 256 threads; thread t owns column j = t
    __shared__ float embI[DD];
    __shared__ float sim[NN];
    __shared__ float redV[4];
    __shared__ int   redI[4];

    if (t < DD) embI[t] = emb[i * DD + t];
    __syncthreads();

    double dot = 0.0;
    #pragma unroll 4
    for (int d = 0; d < DD; ++d) dot += (double)embI[d] * (double)emb[t * DD + d];
    double cosv = dot / (sqrt(nrm2[i]) * sqrt(nrm2[t]) + 1e-8);
    double stdi = sqrt(cov[i * NN + i] + 1e-8);
    double stdj = sqrt(cov[t * NN + t] + 1e-8);
    double corrv = cov[i * NN + t] / (stdi * stdj + 1e-8);
    sim[t] = (float)(0.7 * cosv + 0.3 * corrv);
    __syncthreads();

    int lane = t & 63, wid = t >> 6;
    for (int k = 0; k < KK; ++k) {
        float v = sim[t];
        int idx = t;
        for (int off = 32; off; off >>= 1) {
            float ov = __shfl_down(v, off);
            int   oi = __shfl_down(idx, off);
            if (ov > v || (ov == v && oi < idx)) { v = ov; idx = oi; }
        }
        if (lane == 0) { redV[wid] = v; redI[wid] = idx; }
        __syncthreads();
        if (t == 0) {
            float bv = redV[0]; int bi = redI[0];
            #pragma unroll
            for (int wv = 1; wv < 4; ++wv)
                if (redV[wv] > bv || (redV[wv] == bv && redI[wv] < bi)) { bv = redV[wv]; bi = redI[wv]; }
            topk[i * KK + k] = bi;
            sim[bi] = -3.4e38f;           // remove from candidates
        }
        __syncthreads();
    }
}

// ---------------- Kernel E: xl = x @ lin_W (32 rows/block, lin_W in LDS) ----------------
__global__ __launch_bounds__(128) void k_xl(const float* __restrict__ data,
                                            const float* __restrict__ linW,
                                            float* __restrict__ xl) {
    int t = threadIdx.x;                  // 128 threads, thread t owns output column t
    int r0 = blockIdx.x * 32;
    __shared__ float wt[WW * DD];         // 32 KB
    __shared__ float dt[32][WW];          // 8 KB
    #pragma unroll
    for (int e = 0; e < 64; ++e) wt[t + e * 128] = linW[t + e * 128];
    #pragma unroll
    for (int e = 0; e < 16; ++e) {
        int idx = t + e * 128;
        int r = idx >> 6, w = idx & 63;
        dt[r][w] = data[(r0 + r) * WW + w];
    }
    __syncthreads();
    for (int r = 0; r < 32; ++r) {
        float a0 = 0, a1 = 0, a2 = 0, a3 = 0;
        #pragma unroll
        for (int w = 0; w < WW; w += 4) {
            a0 += dt[r][w + 0] * wt[(w + 0) * DD + t];
            a1 += dt[r][w + 1] * wt[(w + 1) * DD + t];
            a2 += dt[r][w + 2] * wt[(w + 2) * DD + t];
            a3 += dt[r][w + 3] * wt[(w + 3) * DD + t];
        }
        xl[(r0 + r) * DD + t] = (a0 + a1) + (a2 + a3);
    }
}

// ---------------- Kernel E2: s_i_x = xl . att_i, s_j_x = xl . att_j (one wave per row) ---------
__global__ void k_sij(const float* __restrict__ xl,
                      const float* __restrict__ att_i,
                      const float* __restrict__ att_j,
                      float* __restrict__ s_i_x, float* __restrict__ s_j_x) {
    int t = threadIdx.x;                  // 256 threads = 4 waves, one row each
    int lane = t & 63, wv = t >> 6;
    int v = blockIdx.x * 4 + wv;
    float x0 = xl[v * DD + lane];
    float x1 = xl[v * DD + 64 + lane];
    float pi = x0 * att_i[lane] + x1 * att_i[64 + lane];
    float pj = x0 * att_j[lane] + x1 * att_j[64 + lane];
    for (int off = 32; off; off >>= 1) { pi += __shfl_down(pi, off); pj += __shfl_down(pj, off); }
    if (lane == 0) { s_i_x[v] = pi; s_j_x[v] = pj; }
}

// ---------------- Kernel F: attention softmax + aggregate + BN1 + emb-scale + BN2 + out --------
__global__ __launch_bounds__(128) void k_attn_out(
        const float* __restrict__ xl, const int* __restrict__ topk,
        const float* __restrict__ s_i_x, const float* __restrict__ s_j_x,
        const float* __restrict__ eemi, const float* __restrict__ eemj,
        const float* __restrict__ gnn_bias,
        const float* __restrict__ bn1_g, const float* __restrict__ bn1_b,
        const float* __restrict__ bn2_g, const float* __restrict__ bn2_b,
        const float* __restrict__ emb,
        const float* __restrict__ outW, const float* __restrict__ outb,
        float* __restrict__ out) {
    int v = blockIdx.x;                   // v = b*N + i
    int i = v & (NN - 1), b = v >> 8;
    int d = threadIdx.x;                  // 128 threads, one per feature dim

    float sIt = s_i_x[v] + eemi[i];
    int jk[KK];
    float a[KK];
    float amax = -3.4e38f;
    #pragma unroll
    for (int k = 0; k < KK; ++k) {
        int j = topk[i * KK + k];
        jk[k] = j;
        float al = sIt + s_j_x[b * NN + j] + eemj[j];
        al = al > 0.f ? al : 0.2f * al;   // leaky relu
        a[k] = al;
        amax = fmaxf(amax, al);
    }
    float den = 0.f;
    #pragma unroll
    for (int k = 0; k < KK; ++k) { a[k] = expf(a[k] - amax); den += a[k]; }
    float rden = 1.f / den;

    float acc = 0.f;
    #pragma unroll
    for (int k = 0; k < KK; ++k)
        acc += (a[k] * rden) * xl[(b * NN + jk[k]) * DD + d];

    const float bnd = sqrtf(1.0f + 1e-5f);
    float o = acc + gnn_bias[d];
    o = o / bnd * bn1_g[d] + bn1_b[d];
    o = o > 0.f ? o : 0.f;                // relu
    float h = o * emb[i * DD + d];
    h = h / bnd * bn2_g[d] + bn2_b[d];
    h = h > 0.f ? h : 0.f;                // relu

    float partial = h * outW[d];
    for (int off = 32; off; off >>= 1) partial += __shfl_down(partial, off);
    __shared__ float red[2];
    int lane = d & 63, wid = d >> 6;
    if (lane == 0) red[wid] = partial;
    __syncthreads();
    if (d == 0) out[v] = red[0] + red[1] + outb[0];
}

extern "C" void kernel_launch(void* const* d_in, const int* in_sizes, int n_in,
                              void* d_out, int out_size, void* d_ws, size_t ws_size,
                              hipStream_t stream) {
    const float* data     = (const float*)d_in[0];
    // d_in[1] = org_edge_index (unused, as in reference)
    const float* emb      = (const float*)d_in[2];
    const float* linW     = (const float*)d_in[3];
    const float* att_i    = (const float*)d_in[4];
    const float* att_j    = (const float*)d_in[5];
    const float* att_em_i = (const float*)d_in[6];
    const float* att_em_j = (const float*)d_in[7];
    const float* gnn_bias = (const float*)d_in[8];
    const float* bn1_g    = (const float*)d_in[9];
    const float* bn1_b    = (const float*)d_in[10];
    const float* bn2_g    = (const float*)d_in[11];
    const float* bn2_b    = (const float*)d_in[12];
    const float* outW     = (const float*)d_in[13];
    const float* outb     = (const float*)d_in[14];
    float* out = (float*)d_out;

    char* ws = (char*)d_ws;
    double* mean  = (double*)(ws + 0);                       // 2 KB
    double* nrm2  = (double*)(ws + 2048);                    // 2 KB
    float*  eemi  = (float*)(ws + 4096);                     // 1 KB
    float*  eemj  = (float*)(ws + 5120);                     // 1 KB
    int*    topk  = (int*)(ws + 8192);                       // 20 KB
    double* cov   = (double*)(ws + 32768);                   // 512 KB
    float*  xl    = (float*)(ws + (1 << 20));                // 16 MB
    float*  s_i_x = (float*)(ws + (1 << 20) + (16 << 20));   // 128 KB
    float*  s_j_x = (float*)(ws + (1 << 20) + (16 << 20) + (128 << 10)); // 128 KB

    k_mean<<<NN, 256, 0, stream>>>(data, mean);
    k_embstats<<<NN, 128, 0, stream>>>(emb, att_em_i, att_em_j, eemi, eemj, nrm2);
    dim3 gc(NN / CT, NN / CT);
    k_cov<<<gc, 256, 0, stream>>>(data, mean, cov);
    k_sim_topk<<<NN, 256, 0, stream>>>(emb, nrm2, cov, topk);
    k_xl<<<(BB * NN) / 32, 128, 0, stream>>>(data, linW, xl);
    k_sij<<<(BB * NN) / 4, 256, 0, stream>>>(xl, att_i, att_j, s_i_x, s_j_x);
    k_attn_out<<<BB * NN, 128, 0, stream>>>(xl, topk, s_i_x, s_j_x, eemi, eemj, gnn_bias,
                                            bn1_g, bn1_b, bn2_g, bn2_b, emb, outW, outb, out);
}

// Round 2
// 166.638 us; speedup vs baseline: 1.4267x; 1.4267x over previous
//
#include <hip/hip_runtime.h>
#include <math.h>

#define BB 128
#define NN 256
#define WW 64
#define DD 128
#define KK 20
#define LL (BB*WW)   // 8192

#define CI 64        // cov i-tile
#define CJ 32        // cov j-tile
#define SPLIT 16     // cov split-K chunks
#define BPC (BB/SPLIT) // 8 batches per chunk

// ---------------- Kernel A: per-node means of xr (row n = data[:,n,:] flattened) ----------------
__global__ void k_mean(const float* __restrict__ data, double* __restrict__ mean) {
    int n = blockIdx.x;
    int t = threadIdx.x;                  // 256 threads
    double s = 0.0;
    for (int c = 0; c < LL / 256; ++c) {
        int l = t + c * 256;
        int b = l >> 6, w = l & 63;
        s += (double)data[(b * NN + n) * WW + w];
    }
    for (int off = 32; off; off >>= 1) s += __shfl_down(s, off);
    __shared__ double red[4];
    int lane = t & 63, wid = t >> 6;
    if (lane == 0) red[wid] = s;
    __syncthreads();
    if (t == 0) mean[n] = (red[0] + red[1] + red[2] + red[3]) / (double)LL;
}

// ---------------- Kernel B: emb stats: e_em_i, e_em_j, ||emb||^2 ----------------
__global__ void k_embstats(const float* __restrict__ emb,
                           const float* __restrict__ att_em_i,
                           const float* __restrict__ att_em_j,
                           float* __restrict__ eemi, float* __restrict__ eemj,
                           double* __restrict__ nrm2) {
    int n = blockIdx.x;
    int t = threadIdx.x;                  // 128 threads
    float e = emb[n * DD + t];
    float pi = e * att_em_i[t];
    float pj = e * att_em_j[t];
    double pn = (double)e * (double)e;
    for (int off = 32; off; off >>= 1) {
        pi += __shfl_down(pi, off);
        pj += __shfl_down(pj, off);
        pn += __shfl_down(pn, off);
    }
    __shared__ float ri[2], rj[2];
    __shared__ double rn[2];
    int lane = t & 63, wid = t >> 6;
    if (lane == 0) { ri[wid] = pi; rj[wid] = pj; rn[wid] = pn; }
    __syncthreads();
    if (t == 0) { eemi[n] = ri[0] + ri[1]; eemj[n] = rj[0] + rj[1]; nrm2[n] = rn[0] + rn[1]; }
}

// ---------------- Kernel C: split-K covariance partials (fp64 raw moments) ----------------
// 64x32 output tile per block, 256 threads, each thread computes 4x2 outputs.
// LDS tiles stored as fp64 (converted once during staging). Reg-double-buffered staging.
__global__ __launch_bounds__(256) void k_cov2(const float* __restrict__ data,
                                              double* __restrict__ covp) {
    const int i0 = blockIdx.y * CI;
    const int j0 = blockIdx.x * CJ;
    const int bz = blockIdx.z;
    const int t = threadIdx.x;
    const int ti = t >> 4, tj = t & 15;

    __shared__ double2 As2[CI][33];   // stride 33 double2 = 528 B
    __shared__ double2 Bs2[CJ][33];

    float2 ra[8], rb[4];
    const int batch0 = bz * BPC;

    // prefetch batch 0
    #pragma unroll
    for (int e = 0; e < 8; ++e) {
        int fi = t + e * 256, row = fi >> 5, w2 = fi & 31;
        ra[e] = ((const float2*)(data + (batch0 * NN + i0 + row) * WW))[w2];
    }
    #pragma unroll
    for (int e = 0; e < 4; ++e) {
        int fi = t + e * 256, row = fi >> 5, w2 = fi & 31;
        rb[e] = ((const float2*)(data + (batch0 * NN + j0 + row) * WW))[w2];
    }

    double acc[4][2] = {};

    for (int b = 0; b < BPC; ++b) {
        // write staged regs (converted to fp64) into LDS
        #pragma unroll
        for (int e = 0; e < 8; ++e) {
            int fi = t + e * 256, row = fi >> 5, w2 = fi & 31;
            As2[row][w2] = make_double2((double)ra[e].x, (double)ra[e].y);
        }
        #pragma unroll
        for (int e = 0; e < 4; ++e) {
            int fi = t + e * 256, row = fi >> 5, w2 = fi & 31;
            Bs2[row][w2] = make_double2((double)rb[e].x, (double)rb[e].y);
        }
        __syncthreads();

        // prefetch next batch into regs (hides global latency under compute)
        if (b + 1 < BPC) {
            int nb = batch0 + b + 1;
            #pragma unroll
            for (int e = 0; e < 8; ++e) {
                int fi = t + e * 256, row = fi >> 5, w2 = fi & 31;
                ra[e] = ((const float2*)(data + (nb * NN + i0 + row) * WW))[w2];
            }
            #pragma unroll
            for (int e = 0; e < 4; ++e) {
                int fi = t + e * 256, row = fi >> 5, w2 = fi & 31;
                rb[e] = ((const float2*)(data + (nb * NN + j0 + row) * WW))[w2];
            }
        }

        // compute: 32 w-pair steps, 16 fp64 FMAs each
        #pragma unroll 8
        for (int w2 = 0; w2 < 32; ++w2) {
            double2 b0 = Bs2[2 * tj + 0][w2];
            double2 b1 = Bs2[2 * tj + 1][w2];
            #pragma unroll
            for (int r = 0; r < 4; ++r) {
                double2 a = As2[4 * ti + r][w2];
                acc[r][0] += a.x * b0.x;
                acc[r][0] += a.y * b0.y;
                acc[r][1] += a.x * b1.x;
                acc[r][1] += a.y * b1.y;
            }
        }
        __syncthreads();
    }

    #pragma unroll
    for (int r = 0; r < 4; ++r)
        #pragma unroll
        for (int s = 0; s < 2; ++s)
            covp[(bz * NN + i0 + 4 * ti + r) * NN + j0 + 2 * tj + s] = acc[r][s];
}

// ---------------- Kernel C2: reduce split-K partials, subtract mean term ----------------
__global__ void k_cov_reduce(const double* __restrict__ covp,
                             const double* __restrict__ mean,
                             double* __restrict__ cov) {
    int idx = blockIdx.x * 256 + threadIdx.x;   // 0..65535
    int i = idx >> 8, j = idx & 255;
    double s = 0.0;
    #pragma unroll
    for (int z = 0; z < SPLIT; ++z) s += covp[(z * NN + i) * NN + j];
    s -= (double)LL * mean[i] * mean[j];
    cov[i * NN + j] = s;
}

// ---------------- Kernel D: sim = 0.7*cos + 0.3*corr (fp64) -> fp32, then top-20 per row --------
__global__ void k_sim_topk(const float* __restrict__ emb,
                           const double* __restrict__ nrm2,
                           const double* __restrict__ cov,
                           int* __restrict__ topk) {
    int i = blockIdx.x;
    int t = threadIdx.x;                  // 256 threads; thread t owns column j = t
    __shared__ float embI[DD];
    __shared__ float sim[NN];
    __shared__ float redV[4];
    __shared__ int   redI[4];

    if (t < DD) embI[t] = emb[i * DD + t];
    __syncthreads();

    double dot = 0.0;
    #pragma unroll 4
    for (int d = 0; d < DD; ++d) dot += (double)embI[d] * (double)emb[t * DD + d];
    double cosv = dot / (sqrt(nrm2[i]) * sqrt(nrm2[t]) + 1e-8);
    double stdi = sqrt(cov[i * NN + i] + 1e-8);
    double stdj = sqrt(cov[t * NN + t] + 1e-8);
    double corrv = cov[i * NN + t] / (stdi * stdj + 1e-8);
    sim[t] = (float)(0.7 * cosv + 0.3 * corrv);
    __syncthreads();

    int lane = t & 63, wid = t >> 6;
    for (int k = 0; k < KK; ++k) {
        float v = sim[t];
        int idx = t;
        for (int off = 32; off; off >>= 1) {
            float ov = __shfl_down(v, off);
            int   oi = __shfl_down(idx, off);
            if (ov > v || (ov == v && oi < idx)) { v = ov; idx = oi; }
        }
        if (lane == 0) { redV[wid] = v; redI[wid] = idx; }
        __syncthreads();
        if (t == 0) {
            float bv = redV[0]; int bi = redI[0];
            #pragma unroll
            for (int wv = 1; wv < 4; ++wv)
                if (redV[wv] > bv || (redV[wv] == bv && redI[wv] < bi)) { bv = redV[wv]; bi = redI[wv]; }
            topk[i * KK + k] = bi;
            sim[bi] = -3.4e38f;           // remove from candidates
        }
        __syncthreads();
    }
}

// ---------------- Kernel E: xl = x @ lin_W (32 rows/block, lin_W in LDS) ----------------
__global__ __launch_bounds__(128) void k_xl(const float* __restrict__ data,
                                            const float* __restrict__ linW,
                                            float* __restrict__ xl) {
    int t = threadIdx.x;                  // 128 threads, thread t owns output column t
    int r0 = blockIdx.x * 32;
    __shared__ float wt[WW * DD];         // 32 KB
    __shared__ float dt[32][WW];          // 8 KB
    #pragma unroll
    for (int e = 0; e < 64; ++e) wt[t + e * 128] = linW[t + e * 128];
    #pragma unroll
    for (int e = 0; e < 16; ++e) {
        int idx = t + e * 128;
        int r = idx >> 6, w = idx & 63;
        dt[r][w] = data[(r0 + r) * WW + w];
    }
    __syncthreads();
    for (int r = 0; r < 32; ++r) {
        float a0 = 0, a1 = 0, a2 = 0, a3 = 0;
        #pragma unroll
        for (int w = 0; w < WW; w += 4) {
            a0 += dt[r][w + 0] * wt[(w + 0) * DD + t];
            a1 += dt[r][w + 1] * wt[(w + 1) * DD + t];
            a2 += dt[r][w + 2] * wt[(w + 2) * DD + t];
            a3 += dt[r][w + 3] * wt[(w + 3) * DD + t];
        }
        xl[(r0 + r) * DD + t] = (a0 + a1) + (a2 + a3);
    }
}

// ---------------- Kernel E2: s_i_x = xl . att_i, s_j_x = xl . att_j (one wave per row) ---------
__global__ void k_sij(const float* __restrict__ xl,
                      const float* __restrict__ att_i,
                      const float* __restrict__ att_j,
                      float* __restrict__ s_i_x, float* __restrict__ s_j_x) {
    int t = threadIdx.x;                  // 256 threads = 4 waves, one row each
    int lane = t & 63, wv = t >> 6;
    int v = blockIdx.x * 4 + wv;
    float x0 = xl[v * DD + lane];
    float x1 = xl[v * DD + 64 + lane];
    float pi = x0 * att_i[lane] + x1 * att_i[64 + lane];
    float pj = x0 * att_j[lane] + x1 * att_j[64 + lane];
    for (int off = 32; off; off >>= 1) { pi += __shfl_down(pi, off); pj += __shfl_down(pj, off); }
    if (lane == 0) { s_i_x[v] = pi; s_j_x[v] = pj; }
}

// ---------------- Kernel F: attention softmax + aggregate + BN1 + emb-scale + BN2 + out --------
__global__ __launch_bounds__(128) void k_attn_out(
        const float* __restrict__ xl, const int* __restrict__ topk,
        const float* __restrict__ s_i_x, const float* __restrict__ s_j_x,
        const float* __restrict__ eemi, const float* __restrict__ eemj,
        const float* __restrict__ gnn_bias,
        const float* __restrict__ bn1_g, const float* __restrict__ bn1_b,
        const float* __restrict__ bn2_g, const float* __restrict__ bn2_b,
        const float* __restrict__ emb,
        const float* __restrict__ outW, const float* __restrict__ outb,
        float* __restrict__ out) {
    int v = blockIdx.x;                   // v = b*N + i
    int i = v & (NN - 1), b = v >> 8;
    int d = threadIdx.x;                  // 128 threads, one per feature dim

    float sIt = s_i_x[v] + eemi[i];
    int jk[KK];
    float a[KK];
    float amax = -3.4e38f;
    #pragma unroll
    for (int k = 0; k < KK; ++k) {
        int j = topk[i * KK + k];
        jk[k] = j;
        float al = sIt + s_j_x[b * NN + j] + eemj[j];
        al = al > 0.f ? al : 0.2f * al;   // leaky relu
        a[k] = al;
        amax = fmaxf(amax, al);
    }
    float den = 0.f;
    #pragma unroll
    for (int k = 0; k < KK; ++k) { a[k] = expf(a[k] - amax); den += a[k]; }
    float rden = 1.f / den;

    float acc = 0.f;
    #pragma unroll
    for (int k = 0; k < KK; ++k)
        acc += (a[k] * rden) * xl[(b * NN + jk[k]) * DD + d];

    const float bnd = sqrtf(1.0f + 1e-5f);
    float o = acc + gnn_bias[d];
    o = o / bnd * bn1_g[d] + bn1_b[d];
    o = o > 0.f ? o : 0.f;                // relu
    float h = o * emb[i * DD + d];
    h = h / bnd * bn2_g[d] + bn2_b[d];
    h = h > 0.f ? h : 0.f;                // relu

    float partial = h * outW[d];
    for (int off = 32; off; off >>= 1) partial += __shfl_down(partial, off);
    __shared__ float red[2];
    int lane = d & 63, wid = d >> 6;
    if (lane == 0) red[wid] = partial;
    __syncthreads();
    if (d == 0) out[v] = red[0] + red[1] + outb[0];
}

extern "C" void kernel_launch(void* const* d_in, const int* in_sizes, int n_in,
                              void* d_out, int out_size, void* d_ws, size_t ws_size,
                              hipStream_t stream) {
    const float* data     = (const float*)d_in[0];
    // d_in[1] = org_edge_index (unused, as in reference)
    const float* emb      = (const float*)d_in[2];
    const float* linW     = (const float*)d_in[3];
    const float* att_i    = (const float*)d_in[4];
    const float* att_j    = (const float*)d_in[5];
    const float* att_em_i = (const float*)d_in[6];
    const float* att_em_j = (const float*)d_in[7];
    const float* gnn_bias = (const float*)d_in[8];
    const float* bn1_g    = (const float*)d_in[9];
    const float* bn1_b    = (const float*)d_in[10];
    const float* bn2_g    = (const float*)d_in[11];
    const float* bn2_b    = (const float*)d_in[12];
    const float* outW     = (const float*)d_in[13];
    const float* outb     = (const float*)d_in[14];
    float* out = (float*)d_out;

    char* ws = (char*)d_ws;
    double* mean  = (double*)(ws + 0);                       // 2 KB
    double* nrm2  = (double*)(ws + 2048);                    // 2 KB
    float*  eemi  = (float*)(ws + 4096);                     // 1 KB
    float*  eemj  = (float*)(ws + 5120);                     // 1 KB
    int*    topk  = (int*)(ws + 8192);                       // 20 KB
    double* cov   = (double*)(ws + 32768);                   // 512 KB
    // covp (8 MB) aliases the xl region: consumed by k_cov_reduce before k_xl writes xl.
    double* covp  = (double*)(ws + (1 << 20));               // 8 MB (aliased)
    float*  xl    = (float*)(ws + (1 << 20));                // 16 MB
    float*  s_i_x = (float*)(ws + (1 << 20) + (16 << 20));   // 128 KB
    float*  s_j_x = (float*)(ws + (1 << 20) + (16 << 20) + (128 << 10)); // 128 KB

    k_mean<<<NN, 256, 0, stream>>>(data, mean);
    k_embstats<<<NN, 128, 0, stream>>>(emb, att_em_i, att_em_j, eemi, eemj, nrm2);
    dim3 gc(NN / CJ, NN / CI, SPLIT);
    k_cov2<<<gc, 256, 0, stream>>>(data, covp);
    k_cov_reduce<<<NN * NN / 256, 256, 0, stream>>>(covp, mean, cov);
    k_sim_topk<<<NN, 256, 0, stream>>>(emb, nrm2, cov, topk);
    k_xl<<<(BB * NN) / 32, 128, 0, stream>>>(data, linW, xl);
    k_sij<<<(BB * NN) / 4, 256, 0, stream>>>(xl, att_i, att_j, s_i_x, s_j_x);
    k_attn_out<<<BB * NN, 128, 0, stream>>>(xl, topk, s_i_x, s_j_x, eemi, eemj, gnn_bias,
                                            bn1_g, bn1_b, bn2_g, bn2_b, emb, outW, outb, out);
}

// Round 3
// 155.643 us; speedup vs baseline: 1.5274x; 1.0706x over previous
//
#include <hip/hip_runtime.h>
#include <math.h>

#define BB 128
#define NN 256
#define WW 64
#define DD 128
#define KK 20
#define LL (BB*WW)   // 8192

#define CI 64        // cov i-tile
#define CJ 32        // cov j-tile
#define SPLIT 16     // cov split-K chunks
#define BPC (BB/SPLIT) // 8 batches per chunk

// ---------------- Kernel A: per-node means of xr (row n = data[:,n,:] flattened) ----------------
__global__ void k_mean(const float* __restrict__ data, double* __restrict__ mean) {
    int n = blockIdx.x;
    int t = threadIdx.x;                  // 256 threads
    double s = 0.0;
    for (int c = 0; c < LL / 256; ++c) {
        int l = t + c * 256;
        int b = l >> 6, w = l & 63;
        s += (double)data[(b * NN + n) * WW + w];
    }
    for (int off = 32; off; off >>= 1) s += __shfl_down(s, off);
    __shared__ double red[4];
    int lane = t & 63, wid = t >> 6;
    if (lane == 0) red[wid] = s;
    __syncthreads();
    if (t == 0) mean[n] = (red[0] + red[1] + red[2] + red[3]) / (double)LL;
}

// ---------------- Kernel B: emb stats: e_em_i, e_em_j, ||emb||^2 ----------------
__global__ void k_embstats(const float* __restrict__ emb,
                           const float* __restrict__ att_em_i,
                           const float* __restrict__ att_em_j,
                           float* __restrict__ eemi, float* __restrict__ eemj,
                           double* __restrict__ nrm2) {
    int n = blockIdx.x;
    int t = threadIdx.x;                  // 128 threads
    float e = emb[n * DD + t];
    float pi = e * att_em_i[t];
    float pj = e * att_em_j[t];
    double pn = (double)e * (double)e;
    for (int off = 32; off; off >>= 1) {
        pi += __shfl_down(pi, off);
        pj += __shfl_down(pj, off);
        pn += __shfl_down(pn, off);
    }
    __shared__ float ri[2], rj[2];
    __shared__ double rn[2];
    int lane = t & 63, wid = t >> 6;
    if (lane == 0) { ri[wid] = pi; rj[wid] = pj; rn[wid] = pn; }
    __syncthreads();
    if (t == 0) { eemi[n] = ri[0] + ri[1]; eemj[n] = rj[0] + rj[1]; nrm2[n] = rn[0] + rn[1]; }
}

// ---------------- Kernel C: split-K covariance partials (fp64 raw moments) ----------------
__global__ __launch_bounds__(256) void k_cov2(const float* __restrict__ data,
                                              double* __restrict__ covp) {
    const int i0 = blockIdx.y * CI;
    const int j0 = blockIdx.x * CJ;
    const int bz = blockIdx.z;
    const int t = threadIdx.x;
    const int ti = t >> 4, tj = t & 15;

    __shared__ double2 As2[CI][33];   // stride 33 double2 = 528 B
    __shared__ double2 Bs2[CJ][33];

    float2 ra[8], rb[4];
    const int batch0 = bz * BPC;

    #pragma unroll
    for (int e = 0; e < 8; ++e) {
        int fi = t + e * 256, row = fi >> 5, w2 = fi & 31;
        ra[e] = ((const float2*)(data + (batch0 * NN + i0 + row) * WW))[w2];
    }
    #pragma unroll
    for (int e = 0; e < 4; ++e) {
        int fi = t + e * 256, row = fi >> 5, w2 = fi & 31;
        rb[e] = ((const float2*)(data + (batch0 * NN + j0 + row) * WW))[w2];
    }

    double acc[4][2] = {};

    for (int b = 0; b < BPC; ++b) {
        #pragma unroll
        for (int e = 0; e < 8; ++e) {
            int fi = t + e * 256, row = fi >> 5, w2 = fi & 31;
            As2[row][w2] = make_double2((double)ra[e].x, (double)ra[e].y);
        }
        #pragma unroll
        for (int e = 0; e < 4; ++e) {
            int fi = t + e * 256, row = fi >> 5, w2 = fi & 31;
            Bs2[row][w2] = make_double2((double)rb[e].x, (double)rb[e].y);
        }
        __syncthreads();

        if (b + 1 < BPC) {
            int nb = batch0 + b + 1;
            #pragma unroll
            for (int e = 0; e < 8; ++e) {
                int fi = t + e * 256, row = fi >> 5, w2 = fi & 31;
                ra[e] = ((const float2*)(data + (nb * NN + i0 + row) * WW))[w2];
            }
            #pragma unroll
            for (int e = 0; e < 4; ++e) {
                int fi = t + e * 256, row = fi >> 5, w2 = fi & 31;
                rb[e] = ((const float2*)(data + (nb * NN + j0 + row) * WW))[w2];
            }
        }

        #pragma unroll 8
        for (int w2 = 0; w2 < 32; ++w2) {
            double2 b0 = Bs2[2 * tj + 0][w2];
            double2 b1 = Bs2[2 * tj + 1][w2];
            #pragma unroll
            for (int r = 0; r < 4; ++r) {
                double2 a = As2[4 * ti + r][w2];
                acc[r][0] += a.x * b0.x;
                acc[r][0] += a.y * b0.y;
                acc[r][1] += a.x * b1.x;
                acc[r][1] += a.y * b1.y;
            }
        }
        __syncthreads();
    }

    #pragma unroll
    for (int r = 0; r < 4; ++r)
        #pragma unroll
        for (int s = 0; s < 2; ++s)
            covp[(bz * NN + i0 + 4 * ti + r) * NN + j0 + 2 * tj + s] = acc[r][s];
}

// ---------------- Kernel C2: reduce split-K partials, subtract mean term ----------------
__global__ void k_cov_reduce(const double* __restrict__ covp,
                             const double* __restrict__ mean,
                             double* __restrict__ cov) {
    int idx = blockIdx.x * 256 + threadIdx.x;   // 0..65535
    int i = idx >> 8, j = idx & 255;
    double s = 0.0;
    #pragma unroll
    for (int z = 0; z < SPLIT; ++z) s += covp[(z * NN + i) * NN + j];
    s -= (double)LL * mean[i] * mean[j];
    cov[i * NN + j] = s;
}

// ---------------- Kernel D: sim = 0.7*cos + 0.3*corr (fp64) -> fp32, then top-20 per row --------
__global__ void k_sim_topk(const float* __restrict__ emb,
                           const double* __restrict__ nrm2,
                           const double* __restrict__ cov,
                           int* __restrict__ topk) {
    int i = blockIdx.x;
    int t = threadIdx.x;                  // 256 threads; thread t owns column j = t
    __shared__ float embI[DD];
    __shared__ float sim[NN];
    __shared__ float redV[4];
    __shared__ int   redI[4];

    if (t < DD) embI[t] = emb[i * DD + t];
    __syncthreads();

    double dot = 0.0;
    #pragma unroll 4
    for (int d = 0; d < DD; ++d) dot += (double)embI[d] * (double)emb[t * DD + d];
    double cosv = dot / (sqrt(nrm2[i]) * sqrt(nrm2[t]) + 1e-8);
    double stdi = sqrt(cov[i * NN + i] + 1e-8);
    double stdj = sqrt(cov[t * NN + t] + 1e-8);
    double corrv = cov[i * NN + t] / (stdi * stdj + 1e-8);
    sim[t] = (float)(0.7 * cosv + 0.3 * corrv);
    __syncthreads();

    int lane = t & 63, wid = t >> 6;
    for (int k = 0; k < KK; ++k) {
        float v = sim[t];
        int idx = t;
        for (int off = 32; off; off >>= 1) {
            float ov = __shfl_down(v, off);
            int   oi = __shfl_down(idx, off);
            if (ov > v || (ov == v && oi < idx)) { v = ov; idx = oi; }
        }
        if (lane == 0) { redV[wid] = v; redI[wid] = idx; }
        __syncthreads();
        if (t == 0) {
            float bv = redV[0]; int bi = redI[0];
            #pragma unroll
            for (int wv = 1; wv < 4; ++wv)
                if (redV[wv] > bv || (redV[wv] == bv && redI[wv] < bi)) { bv = redV[wv]; bi = redI[wv]; }
            topk[i * KK + k] = bi;
            sim[bi] = -3.4e38f;           // remove from candidates
        }
        __syncthreads();
    }
}

// ---------------- Kernel E: xl = x @ lin_W (32 rows/block, lin_W in LDS) ----------------
__global__ __launch_bounds__(128) void k_xl(const float* __restrict__ data,
                                            const float* __restrict__ linW,
                                            float* __restrict__ xl) {
    int t = threadIdx.x;                  // 128 threads, thread t owns output column t
    int r0 = blockIdx.x * 32;
    __shared__ float wt[WW * DD];         // 32 KB
    __shared__ float dt[32][WW];          // 8 KB
    #pragma unroll
    for (int e = 0; e < 64; ++e) wt[t + e * 128] = linW[t + e * 128];
    #pragma unroll
    for (int e = 0; e < 16; ++e) {
        int idx = t + e * 128;
        int r = idx >> 6, w = idx & 63;
        dt[r][w] = data[(r0 + r) * WW + w];
    }
    __syncthreads();
    for (int r = 0; r < 32; ++r) {
        float a0 = 0, a1 = 0, a2 = 0, a3 = 0;
        #pragma unroll
        for (int w = 0; w < WW; w += 4) {
            a0 += dt[r][w + 0] * wt[(w + 0) * DD + t];
            a1 += dt[r][w + 1] * wt[(w + 1) * DD + t];
            a2 += dt[r][w + 2] * wt[(w + 2) * DD + t];
            a3 += dt[r][w + 3] * wt[(w + 3) * DD + t];
        }
        xl[(r0 + r) * DD + t] = (a0 + a1) + (a2 + a3);
    }
}

// ---------------- Kernel F: fused attention, batch-local LDS gather ----------------
// Block = (half h, batch b). Stages xl[b] (128 KB) in LDS, computes s_i/s_j in-block,
// per-node softmax with lanes 0..19, gathers neighbor rows from LDS, fused epilogue.
__global__ __launch_bounds__(512) void k_attn_fused(
        const float* __restrict__ xl, const int* __restrict__ topk,
        const float* __restrict__ att_i, const float* __restrict__ att_j,
        const float* __restrict__ eemi, const float* __restrict__ eemj,
        const float* __restrict__ gnn_bias,
        const float* __restrict__ bn1_g, const float* __restrict__ bn1_b,
        const float* __restrict__ bn2_g, const float* __restrict__ bn2_b,
        const float* __restrict__ emb,
        const float* __restrict__ outW, const float* __restrict__ outb,
        float* __restrict__ out) {
    const int h = blockIdx.x;             // node half: 0 or 1
    const int b = blockIdx.y;             // batch
    const int t = threadIdx.x;            // 512 threads = 8 waves
    const int lane = t & 63, wv = t >> 6;

    __shared__ float xls[NN * DD];        // 128 KB: xl[b]
    __shared__ float sil[NN], sjl[NN];    // per-node score components

    // ---- stage xl[b] (fully coalesced float4) ----
    {
        const float4* src = (const float4*)(xl + (size_t)b * NN * DD);
        float4* dst = (float4*)xls;
        #pragma unroll
        for (int e = 0; e < 16; ++e) dst[t + e * 512] = src[t + e * 512];
    }
    __syncthreads();

    // ---- per-node attention dot products: si/sj for all 256 nodes ----
    const float2 ai2 = ((const float2*)att_i)[lane];
    const float2 aj2 = ((const float2*)att_j)[lane];
    for (int r = 0; r < 32; ++r) {
        int j = wv * 32 + r;
        float2 xr = *(const float2*)&xls[j * DD + 2 * lane];
        float pi = xr.x * ai2.x + xr.y * ai2.y;
        float pj = xr.x * aj2.x + xr.y * aj2.y;
        #pragma unroll
        for (int off = 32; off; off >>= 1) {
            pi += __shfl_xor(pi, off);
            pj += __shfl_xor(pj, off);
        }
        if (lane == 0) { sil[j] = pi + eemi[j]; sjl[j] = pj + eemj[j]; }
    }
    __syncthreads();

    // ---- per-lane epilogue constants (dims d0=2*lane, d1=2*lane+1) ----
    const float rbnd = 1.0f / sqrtf(1.0f + 1e-5f);
    const float2 gb2 = ((const float2*)gnn_bias)[lane];
    const float2 g12 = ((const float2*)bn1_g)[lane];
    const float2 b12 = ((const float2*)bn1_b)[lane];
    const float2 g22 = ((const float2*)bn2_g)[lane];
    const float2 b22 = ((const float2*)bn2_b)[lane];
    const float2 ow2 = ((const float2*)outW)[lane];
    const float ob0 = outb[0];

    // ---- each wave handles 16 nodes ----
    for (int n = 0; n < 16; ++n) {
        int i = h * 128 + wv * 16 + n;    // node index within batch
        int jl = 0;
        float al = -3.4e38f;
        if (lane < KK) {
            jl = topk[i * KK + lane];
            float sc = sil[i] + sjl[jl];
            al = sc > 0.f ? sc : 0.2f * sc;   // leaky relu
        }
        float m = al;
        #pragma unroll
        for (int off = 32; off; off >>= 1) m = fmaxf(m, __shfl_xor(m, off));
        float e = (lane < KK) ? expf(al - m) : 0.f;
        float s = e;
        #pragma unroll
        for (int off = 32; off; off >>= 1) s += __shfl_xor(s, off);
        float wgt = e / s;

        float accx = 0.f, accy = 0.f;
        #pragma unroll
        for (int k = 0; k < KK; ++k) {
            int j = __shfl(jl, k);
            float wk = __shfl(wgt, k);
            float2 xv = *(const float2*)&xls[j * DD + 2 * lane];
            accx += wk * xv.x;
            accy += wk * xv.y;
        }

        float2 em = *(const float2*)&emb[(size_t)i * DD + 2 * lane];
        float o0 = (accx + gb2.x) * rbnd * g12.x + b12.x; o0 = fmaxf(o0, 0.f);
        float o1 = (accy + gb2.y) * rbnd * g12.y + b12.y; o1 = fmaxf(o1, 0.f);
        float h0 = o0 * em.x; h0 = h0 * rbnd * g22.x + b22.x; h0 = fmaxf(h0, 0.f);
        float h1 = o1 * em.y; h1 = h1 * rbnd * g22.y + b22.y; h1 = fmaxf(h1, 0.f);

        float p = h0 * ow2.x + h1 * ow2.y;
        #pragma unroll
        for (int off = 32; off; off >>= 1) p += __shfl_xor(p, off);
        if (lane == 0) out[b * NN + i] = p + ob0;
    }
}

extern "C" void kernel_launch(void* const* d_in, const int* in_sizes, int n_in,
                              void* d_out, int out_size, void* d_ws, size_t ws_size,
                              hipStream_t stream) {
    const float* data     = (const float*)d_in[0];
    // d_in[1] = org_edge_index (unused, as in reference)
    const float* emb      = (const float*)d_in[2];
    const float* linW     = (const float*)d_in[3];
    const float* att_i    = (const float*)d_in[4];
    const float* att_j    = (const float*)d_in[5];
    const float* att_em_i = (const float*)d_in[6];
    const float* att_em_j = (const float*)d_in[7];
    const float* gnn_bias = (const float*)d_in[8];
    const float* bn1_g    = (const float*)d_in[9];
    const float* bn1_b    = (const float*)d_in[10];
    const float* bn2_g    = (const float*)d_in[11];
    const float* bn2_b    = (const float*)d_in[12];
    const float* outW     = (const float*)d_in[13];
    const float* outb     = (const float*)d_in[14];
    float* out = (float*)d_out;

    char* ws = (char*)d_ws;
    double* mean  = (double*)(ws + 0);                       // 2 KB
    double* nrm2  = (double*)(ws + 2048);                    // 2 KB
    float*  eemi  = (float*)(ws + 4096);                     // 1 KB
    float*  eemj  = (float*)(ws + 5120);                     // 1 KB
    int*    topk  = (int*)(ws + 8192);                       // 20 KB
    double* cov   = (double*)(ws + 32768);                   // 512 KB
    // covp (8 MB) aliases the xl region: consumed by k_cov_reduce before k_xl writes xl.
    double* covp  = (double*)(ws + (1 << 20));               // 8 MB (aliased)
    float*  xl    = (float*)(ws + (1 << 20));                // 16 MB

    k_mean<<<NN, 256, 0, stream>>>(data, mean);
    k_embstats<<<NN, 128, 0, stream>>>(emb, att_em_i, att_em_j, eemi, eemj, nrm2);
    dim3 gc(NN / CJ, NN / CI, SPLIT);
    k_cov2<<<gc, 256, 0, stream>>>(data, covp);
    k_cov_reduce<<<NN * NN / 256, 256, 0, stream>>>(covp, mean, cov);
    k_sim_topk<<<NN, 256, 0, stream>>>(emb, nrm2, cov, topk);
    k_xl<<<(BB * NN) / 32, 128, 0, stream>>>(data, linW, xl);
    dim3 ga(2, BB);
    k_attn_fused<<<ga, 512, 0, stream>>>(xl, topk, att_i, att_j, eemi, eemj, gnn_bias,
                                         bn1_g, bn1_b, bn2_g, bn2_b, emb, outW, outb, out);
}